// Round 3
// baseline (228.374 us; speedup 1.0000x reference)
//
#include <hip/hip_runtime.h>

// PDELoss fused, wave-autonomous version.
// Each 64-lane wave owns one (image, 8-row strip); thread = 4 columns (float4).
// No LDS / no __syncthreads in the hot loop: horizontal halos via __shfl,
// rolling 3-row register window, 1-iteration prefetch distance on pred & rhs.
// GS_ope[c] = sum_{u,v} pred[g+u][c+v] * coef4[u*3+v][c&3], coef folded with
// (KL + KD/r)*alfa/(hr^2 hz^2); Gauss 3x3 separable: horiz from shuffled gs,
// vert via rolling gh registers; MSE accumulated per-thread -> wave shuffle
// reduce -> one atomicAdd per block.
//
// R1: strip 16->8 rows, grid 1024->2048 blocks (fills 8192-wave machine).
// R2: (256,8) capped VGPR at 64 -> compiler squeezed to 32 -> scratch spill
//     (WRITE 82MB, FETCH 453MB). (256,4) at 52 VGPR: no spill but occupancy
//     pinned at ~35% across grid sizes.
// R3: drop the min-waves arg entirely. Evidence: occupancy tracked ONLY the
//     2nd launch_bounds arg (4 -> 33-35%, 8 -> 85%), never grid or VGPR —
//     hipcc's amdgpu-waves-per-eu acts as a residency cap, not just a floor.
//     Bare (256): compiler allocates ~52-60 VGPR (<=64 tier, 8 waves/SIMD
//     possible), no attribute cap.

__global__ __launch_bounds__(256)
void pde_loss_kernel(const float* __restrict__ pred,   // [B,256,256]
                     const float* __restrict__ rhs,    // [B,254,254]
                     const float* __restrict__ KL,     // [B,3,3]
                     const float* __restrict__ KD,     // [B,3,3]
                     const float* __restrict__ RR,     // [B,256,256] (col-only)
                     const float* __restrict__ ZZ,     // [B,256,256] (row-only)
                     float* __restrict__ out,
                     float inv_n)
{
    constexpr int H = 256, W = 256, OH = 254, OW = 254;
    constexpr int SR = 8;                 // strip rows
    const int tid = threadIdx.x;
    const int l   = tid & 63;          // lane
    const int wv  = tid >> 6;          // wave in block
    const int b   = blockIdx.x >> 3;   // image
    const int strip = (blockIdx.x & 7) * 4 + wv;   // 32 strips of 8 rows
    const int o0 = strip * SR;
    const int o1 = (o0 + SR < OH) ? (o0 + SR) : OH;   // last strip: 6 rows

    const size_t ib = (size_t)b * H * W;
    const float* predb = pred + ib;
    const float* rhsb  = rhs + (size_t)b * OH * OW;

    const float hr  = RR[ib + W + 2] - RR[ib + W + 1];
    const float hz  = ZZ[ib + 2 * W + 1] - ZZ[ib + W + 1];
    const float hr2 = hr * hr, hz2 = hz * hz;
    const float s   = -2.0f * (hr2 + hz2) / (hr2 * hz2);

    // Per-column folded coefficients: c4[t] over the 4 owned cols c0..c0+3
    const int c0 = 4 * l;
    float4 c4[9];
    {
        float4 invr;
        invr.x = 1.0f / RR[ib + W + (c0 + 1)];
        invr.y = 1.0f / RR[ib + W + (c0 + 2)];
        invr.z = 1.0f / RR[ib + W + (c0 + 3)];
        invr.w = 1.0f / RR[ib + W + ((c0 + 4 < W) ? (c0 + 4) : (W - 1))];
        const float* kl = KL + b * 9;
        const float* kd = KD + b * 9;
#pragma unroll
        for (int t = 0; t < 9; ++t) {
            const float a = kl[t] * s, d = kd[t] * s;
            c4[t].x = fmaf(d, invr.x, a);
            c4[t].y = fmaf(d, invr.y, a);
            c4[t].z = fmaf(d, invr.z, a);
            c4[t].w = fmaf(d, invr.w, a);
        }
    }

    // Prologue: rolling pred rows g, g+1, g+2 (as pa, pb, pc) + their halos
    const int g0 = o0 - 1;
    float4 pa = make_float4(0.f, 0.f, 0.f, 0.f), pb, pc;
    if (g0 >= 0) pa = *(const float4*)(predb + (size_t)g0 * W + c0);
    pb = *(const float4*)(predb + (size_t)(g0 + 1) * W + c0);
    pc = *(const float4*)(predb + (size_t)(g0 + 2) * W + c0);
    float nxa = __shfl(pa.x, l + 1, 64), nya = __shfl(pa.y, l + 1, 64);
    float nxb = __shfl(pb.x, l + 1, 64), nyb = __shfl(pb.y, l + 1, 64);

    float4 ghA = make_float4(0.f, 0.f, 0.f, 0.f);
    float4 ghB = make_float4(0.f, 0.f, 0.f, 0.f);
    float2 rc0 = make_float2(0.f, 0.f), rc1 = make_float2(0.f, 0.f);
    float acc = 0.0f;

    for (int g = g0; g <= o1; ++g) {
        // --- prefetch pred row g+3 (consumed next iteration as pc) ---
        float4 pn = make_float4(0.f, 0.f, 0.f, 0.f);
        const int rowp = g + 3;
        if (rowp < H && rowp <= o1 + 2)
            pn = *(const float4*)(predb + (size_t)rowp * W + c0);

        // --- prefetch rhs row g (consumed next iteration at emit i=g) ---
        float2 rn0 = make_float2(0.f, 0.f), rn1 = make_float2(0.f, 0.f);
        if (g >= o0 && g < o1) {
            const float* rrow = rhsb + (size_t)g * OW + c0;
            rn0 = *(const float2*)rrow;
            if (c0 + 2 < OW) rn1 = *(const float2*)(rrow + 2);
        }

        // --- halos for the row newly in position c (loaded last iter) ---
        const float nxc = __shfl(pc.x, l + 1, 64);
        const float nyc = __shfl(pc.y, l + 1, 64);

        // --- GS_ope row g (zero outside [0,OH): SAME padding) ---
        float4 gs = make_float4(0.f, 0.f, 0.f, 0.f);
        if ((unsigned)g < (unsigned)OH) {
#define ROWC(p, nx, ny, t0)                                              \
            gs.x = fmaf(p.x, c4[t0].x, fmaf(p.y, c4[t0+1].x, fmaf(p.z, c4[t0+2].x, gs.x))); \
            gs.y = fmaf(p.y, c4[t0].y, fmaf(p.z, c4[t0+1].y, fmaf(p.w, c4[t0+2].y, gs.y))); \
            gs.z = fmaf(p.z, c4[t0].z, fmaf(p.w, c4[t0+1].z, fmaf(nx,  c4[t0+2].z, gs.z))); \
            gs.w = fmaf(p.w, c4[t0].w, fmaf(nx,  c4[t0+1].w, fmaf(ny,  c4[t0+2].w, gs.w)));
            ROWC(pa, nxa, nya, 0)
            ROWC(pb, nxb, nyb, 3)
            ROWC(pc, nxc, nyc, 6)
#undef ROWC
            if (l == 63) { gs.z = 0.f; gs.w = 0.f; }   // cols 254,255 out of range
        }

        // --- horizontal [1,2,1] ---
        float up = __shfl(gs.w, l - 1, 64);
        const float dn = __shfl(gs.x, l + 1, 64);     // lane 63: garbage, unused
        if (l == 0) up = 0.f;
        float4 gh;
        gh.x = fmaf(2.f, gs.x, up   + gs.y);
        gh.y = fmaf(2.f, gs.y, gs.x + gs.z);
        gh.z = fmaf(2.f, gs.z, gs.y + gs.w);
        gh.w = fmaf(2.f, gs.w, gs.z + dn);

        // --- vertical [1,2,1]/16, emit row i = g-1, MSE accumulate ---
        const int i = g - 1;
        if (i >= o0 && i < o1) {
            const float smx = (ghA.x + 2.f * ghB.x + gh.x) * 0.0625f;
            const float smy = (ghA.y + 2.f * ghB.y + gh.y) * 0.0625f;
            const float smz = (ghA.z + 2.f * ghB.z + gh.z) * 0.0625f;
            const float smw = (ghA.w + 2.f * ghB.w + gh.w) * 0.0625f;
            const float dx = smx - rc0.x;
            const float dy = smy - rc0.y;
            float dz = smz - rc1.x;
            float dw = smw - rc1.y;
            if (c0 + 2 >= OW) { dz = 0.f; dw = 0.f; }   // lane 63 tail cols
            acc = fmaf(dx, dx, acc);
            acc = fmaf(dy, dy, acc);
            acc = fmaf(dz, dz, acc);
            acc = fmaf(dw, dw, acc);
        }

        // --- roll ---
        pa = pb; pb = pc; pc = pn;
        nxa = nxb; nya = nyb; nxb = nxc; nyb = nyc;
        ghA = ghB; ghB = gh;
        rc0 = rn0; rc1 = rn1;
    }

    // wave reduce -> block reduce -> one atomic per block
#pragma unroll
    for (int off = 32; off > 0; off >>= 1)
        acc += __shfl_down(acc, off, 64);
    __shared__ float wsum[4];
    if (l == 0) wsum[wv] = acc;
    __syncthreads();
    if (tid == 0) {
        const float t = (wsum[0] + wsum[1]) + (wsum[2] + wsum[3]);
        atomicAdd(out, t * inv_n);
    }
}

extern "C" void kernel_launch(void* const* d_in, const int* in_sizes, int n_in,
                              void* d_out, int out_size, void* d_ws, size_t ws_size,
                              hipStream_t stream) {
    const float* pred = (const float*)d_in[0];
    const float* rhs  = (const float*)d_in[1];
    const float* KL   = (const float*)d_in[2];
    const float* KD   = (const float*)d_in[3];
    const float* RR   = (const float*)d_in[4];
    const float* ZZ   = (const float*)d_in[5];
    // d_in[6] = Gauss kernel [[1,2,1],[2,4,2],[1,2,1]]/16 — hardcoded, separable
    float* out = (float*)d_out;

    const int B = in_sizes[2] / 9;   // 256
    const float inv_n = 1.0f / ((float)B * 254.0f * 254.0f);

    hipMemsetAsync(out, 0, sizeof(float), stream);
    pde_loss_kernel<<<dim3(B * 8), dim3(256), 0, stream>>>(pred, rhs, KL, KD, RR, ZZ, out, inv_n);
}

// Round 4
// 216.911 us; speedup vs baseline: 1.0528x; 1.0528x over previous
//
#include <hip/hip_runtime.h>

// PDELoss fused, wave-autonomous version.
// Each 64-lane wave owns one (image, 8-row strip); thread = 4 columns (float4).
// No LDS / no __syncthreads in the hot loop: horizontal halos via __shfl,
// rolling 3-row register window, 1-iteration prefetch distance on pred & rhs.
// GS_ope[c] = sum_{u,v} pred[g+u][c+v] * coef4[u*3+v][c&3], coef folded with
// (KL + KD/r)*alfa/(hr^2 hz^2); Gauss 3x3 separable: horiz from shuffled gs,
// vert via rolling gh registers; MSE accumulated per-thread -> wave shuffle
// reduce -> per-block partial -> separate tiny reduce kernel.
//
// R1: strip 16->8 rows, grid 1024->2048 blocks (fills 8192-wave machine).
// R2: (256,8) capped VGPR at 64 -> 32 -> scratch spill (WRITE 82MB). Reverted.
// R3: bare launch_bounds == (256,4): identical 52 VGPR, identical 35% occ.
//     Residency pins at ~11 waves/CU across grid sizes; time tracks total
//     wave-iters, not parallelism; VALU 22% / HBM 16% / no spills.
// R4: kill the epilogue atomic storm. 2048 co-resident blocks all hit
//     atomicAdd(out) on ONE address at once -> serialized cross-XCD tail
//     (~25ns/op ~= the unexplained ~45us; depresses time-avg Occ/VALUBusy).
//     Blocks now store partials to d_ws (contention-free), second 1-block
//     kernel reduces 2048 floats. Hot loop untouched (still 52 VGPR).

__global__ __launch_bounds__(256, 4)
void pde_loss_kernel(const float* __restrict__ pred,   // [B,256,256]
                     const float* __restrict__ rhs,    // [B,254,254]
                     const float* __restrict__ KL,     // [B,3,3]
                     const float* __restrict__ KD,     // [B,3,3]
                     const float* __restrict__ RR,     // [B,256,256] (col-only)
                     const float* __restrict__ ZZ,     // [B,256,256] (row-only)
                     float* __restrict__ partials)     // [gridDim.x]
{
    constexpr int H = 256, W = 256, OH = 254, OW = 254;
    constexpr int SR = 8;                 // strip rows
    const int tid = threadIdx.x;
    const int l   = tid & 63;          // lane
    const int wv  = tid >> 6;          // wave in block
    const int b   = blockIdx.x >> 3;   // image
    const int strip = (blockIdx.x & 7) * 4 + wv;   // 32 strips of 8 rows
    const int o0 = strip * SR;
    const int o1 = (o0 + SR < OH) ? (o0 + SR) : OH;   // last strip: 6 rows

    const size_t ib = (size_t)b * H * W;
    const float* predb = pred + ib;
    const float* rhsb  = rhs + (size_t)b * OH * OW;

    const float hr  = RR[ib + W + 2] - RR[ib + W + 1];
    const float hz  = ZZ[ib + 2 * W + 1] - ZZ[ib + W + 1];
    const float hr2 = hr * hr, hz2 = hz * hz;
    const float s   = -2.0f * (hr2 + hz2) / (hr2 * hz2);

    // Per-column folded coefficients: c4[t] over the 4 owned cols c0..c0+3
    const int c0 = 4 * l;
    float4 c4[9];
    {
        float4 invr;
        invr.x = 1.0f / RR[ib + W + (c0 + 1)];
        invr.y = 1.0f / RR[ib + W + (c0 + 2)];
        invr.z = 1.0f / RR[ib + W + (c0 + 3)];
        invr.w = 1.0f / RR[ib + W + ((c0 + 4 < W) ? (c0 + 4) : (W - 1))];
        const float* kl = KL + b * 9;
        const float* kd = KD + b * 9;
#pragma unroll
        for (int t = 0; t < 9; ++t) {
            const float a = kl[t] * s, d = kd[t] * s;
            c4[t].x = fmaf(d, invr.x, a);
            c4[t].y = fmaf(d, invr.y, a);
            c4[t].z = fmaf(d, invr.z, a);
            c4[t].w = fmaf(d, invr.w, a);
        }
    }

    // Prologue: rolling pred rows g, g+1, g+2 (as pa, pb, pc) + their halos
    const int g0 = o0 - 1;
    float4 pa = make_float4(0.f, 0.f, 0.f, 0.f), pb, pc;
    if (g0 >= 0) pa = *(const float4*)(predb + (size_t)g0 * W + c0);
    pb = *(const float4*)(predb + (size_t)(g0 + 1) * W + c0);
    pc = *(const float4*)(predb + (size_t)(g0 + 2) * W + c0);
    float nxa = __shfl(pa.x, l + 1, 64), nya = __shfl(pa.y, l + 1, 64);
    float nxb = __shfl(pb.x, l + 1, 64), nyb = __shfl(pb.y, l + 1, 64);

    float4 ghA = make_float4(0.f, 0.f, 0.f, 0.f);
    float4 ghB = make_float4(0.f, 0.f, 0.f, 0.f);
    float2 rc0 = make_float2(0.f, 0.f), rc1 = make_float2(0.f, 0.f);
    float acc = 0.0f;

    for (int g = g0; g <= o1; ++g) {
        // --- prefetch pred row g+3 (consumed next iteration as pc) ---
        float4 pn = make_float4(0.f, 0.f, 0.f, 0.f);
        const int rowp = g + 3;
        if (rowp < H && rowp <= o1 + 2)
            pn = *(const float4*)(predb + (size_t)rowp * W + c0);

        // --- prefetch rhs row g (consumed next iteration at emit i=g) ---
        float2 rn0 = make_float2(0.f, 0.f), rn1 = make_float2(0.f, 0.f);
        if (g >= o0 && g < o1) {
            const float* rrow = rhsb + (size_t)g * OW + c0;
            rn0 = *(const float2*)rrow;
            if (c0 + 2 < OW) rn1 = *(const float2*)(rrow + 2);
        }

        // --- halos for the row newly in position c (loaded last iter) ---
        const float nxc = __shfl(pc.x, l + 1, 64);
        const float nyc = __shfl(pc.y, l + 1, 64);

        // --- GS_ope row g (zero outside [0,OH): SAME padding) ---
        float4 gs = make_float4(0.f, 0.f, 0.f, 0.f);
        if ((unsigned)g < (unsigned)OH) {
#define ROWC(p, nx, ny, t0)                                              \
            gs.x = fmaf(p.x, c4[t0].x, fmaf(p.y, c4[t0+1].x, fmaf(p.z, c4[t0+2].x, gs.x))); \
            gs.y = fmaf(p.y, c4[t0].y, fmaf(p.z, c4[t0+1].y, fmaf(p.w, c4[t0+2].y, gs.y))); \
            gs.z = fmaf(p.z, c4[t0].z, fmaf(p.w, c4[t0+1].z, fmaf(nx,  c4[t0+2].z, gs.z))); \
            gs.w = fmaf(p.w, c4[t0].w, fmaf(nx,  c4[t0+1].w, fmaf(ny,  c4[t0+2].w, gs.w)));
            ROWC(pa, nxa, nya, 0)
            ROWC(pb, nxb, nyb, 3)
            ROWC(pc, nxc, nyc, 6)
#undef ROWC
            if (l == 63) { gs.z = 0.f; gs.w = 0.f; }   // cols 254,255 out of range
        }

        // --- horizontal [1,2,1] ---
        float up = __shfl(gs.w, l - 1, 64);
        const float dn = __shfl(gs.x, l + 1, 64);     // lane 63: garbage, unused
        if (l == 0) up = 0.f;
        float4 gh;
        gh.x = fmaf(2.f, gs.x, up   + gs.y);
        gh.y = fmaf(2.f, gs.y, gs.x + gs.z);
        gh.z = fmaf(2.f, gs.z, gs.y + gs.w);
        gh.w = fmaf(2.f, gs.w, gs.z + dn);

        // --- vertical [1,2,1]/16, emit row i = g-1, MSE accumulate ---
        const int i = g - 1;
        if (i >= o0 && i < o1) {
            const float smx = (ghA.x + 2.f * ghB.x + gh.x) * 0.0625f;
            const float smy = (ghA.y + 2.f * ghB.y + gh.y) * 0.0625f;
            const float smz = (ghA.z + 2.f * ghB.z + gh.z) * 0.0625f;
            const float smw = (ghA.w + 2.f * ghB.w + gh.w) * 0.0625f;
            const float dx = smx - rc0.x;
            const float dy = smy - rc0.y;
            float dz = smz - rc1.x;
            float dw = smw - rc1.y;
            if (c0 + 2 >= OW) { dz = 0.f; dw = 0.f; }   // lane 63 tail cols
            acc = fmaf(dx, dx, acc);
            acc = fmaf(dy, dy, acc);
            acc = fmaf(dz, dz, acc);
            acc = fmaf(dw, dw, acc);
        }

        // --- roll ---
        pa = pb; pb = pc; pc = pn;
        nxa = nxb; nya = nyb; nxb = nxc; nyb = nyc;
        ghA = ghB; ghB = gh;
        rc0 = rn0; rc1 = rn1;
    }

    // wave reduce -> block partial -> ONE contention-free store per block
#pragma unroll
    for (int off = 32; off > 0; off >>= 1)
        acc += __shfl_down(acc, off, 64);
    __shared__ float wsum[4];
    if (l == 0) wsum[wv] = acc;
    __syncthreads();
    if (tid == 0)
        partials[blockIdx.x] = (wsum[0] + wsum[1]) + (wsum[2] + wsum[3]);
}

// Second stage: reduce N partials -> out (single block). Also applies inv_n,
// so no memset dispatch is needed anywhere.
__global__ __launch_bounds__(256)
void reduce_kernel(const float* __restrict__ partials, float* __restrict__ out,
                   int n, float inv_n)
{
    const int tid = threadIdx.x;
    float a = 0.0f;
    for (int i = tid; i < n; i += 256) a += partials[i];
#pragma unroll
    for (int off = 32; off > 0; off >>= 1)
        a += __shfl_down(a, off, 64);
    __shared__ float w[4];
    if ((tid & 63) == 0) w[tid >> 6] = a;
    __syncthreads();
    if (tid == 0) out[0] = ((w[0] + w[1]) + (w[2] + w[3])) * inv_n;
}

// Fallback (ws too small): original atomic epilogue.
__global__ __launch_bounds__(256, 4)
void reduce_fallback_zero(float* __restrict__ out) { if (threadIdx.x == 0) out[0] = 0.f; }

extern "C" void kernel_launch(void* const* d_in, const int* in_sizes, int n_in,
                              void* d_out, int out_size, void* d_ws, size_t ws_size,
                              hipStream_t stream) {
    const float* pred = (const float*)d_in[0];
    const float* rhs  = (const float*)d_in[1];
    const float* KL   = (const float*)d_in[2];
    const float* KD   = (const float*)d_in[3];
    const float* RR   = (const float*)d_in[4];
    const float* ZZ   = (const float*)d_in[5];
    // d_in[6] = Gauss kernel [[1,2,1],[2,4,2],[1,2,1]]/16 — hardcoded, separable
    float* out = (float*)d_out;

    const int B = in_sizes[2] / 9;   // 256
    const int nblocks = B * 8;
    const float inv_n = 1.0f / ((float)B * 254.0f * 254.0f);

    float* partials = (float*)d_ws;   // nblocks floats; harness ws is ample
    pde_loss_kernel<<<dim3(nblocks), dim3(256), 0, stream>>>(
        pred, rhs, KL, KD, RR, ZZ, partials);
    reduce_kernel<<<dim3(1), dim3(256), 0, stream>>>(partials, out, nblocks, inv_n);
}

// Round 5
// 212.679 us; speedup vs baseline: 1.0738x; 1.0199x over previous
//
#include <hip/hip_runtime.h>

// PDELoss fused, wave-autonomous version.
// Each 64-lane wave owns one (image, 8-row strip); thread = 4 columns (float4).
// No LDS / no __syncthreads in the hot loop: horizontal halos via __shfl,
// rolling 3-row register window; 2-row unrolled body with all loads issued at
// body top (2-deep effective prefetch). GS_ope = per-col folded stencil
// (KL + KD/r)*alfa/(hr^2 hz^2); Gauss 3x3 separable: horiz via shuffles,
// vert via phase registers; MSE -> wave reduce -> per-block partial ->
// tiny reduce kernel.
//
// R1: strip 16->8 rows, grid 2048 (fill machine): occupancy unmoved (~35%).
// R2: (256,8) VGPR-capped to 32 -> scratch spill. Reverted.
// R3: bare launch_bounds == (256,4): identical. Residency pins ~3 waves/SIMD
//     in every fast config regardless of grid; static math allows 8.
// R4: atomic storm removed (partials + reduce kernel): 65->54us. VALU 27%,
//     ~1000 idle cyc/iter/SIMD remain: per-wave latency exposure, not TLP.
// R5: buy ILP instead of TLP. 2-row unrolled body: roll-movs become register
//     renaming, loads hoisted to body top (pr4/rB get a full body of cover);
//     lane-63 masks folded into c4 (zero .z/.w) + mask-mul instead of
//     cmp/cndmask per iter; 512-thread blocks (8 waves) to test block-paced
//     residency. VGPR ~110 -> 16 waves/CU tier, above the ~12 ever observed.

__global__ __launch_bounds__(512, 1)
void pde_loss_kernel(const float* __restrict__ pred,   // [B,256,256]
                     const float* __restrict__ rhs,    // [B,254,254]
                     const float* __restrict__ KL,     // [B,3,3]
                     const float* __restrict__ KD,     // [B,3,3]
                     const float* __restrict__ RR,     // [B,256,256] (col-only)
                     const float* __restrict__ ZZ,     // [B,256,256] (row-only)
                     float* __restrict__ partials)     // [gridDim.x]
{
    constexpr int H = 256, W = 256, OH = 254, OW = 254, SR = 8;
    const int tid = threadIdx.x;
    const int l   = tid & 63;          // lane
    const int wv  = tid >> 6;          // wave in block (0..7)
    const int b   = blockIdx.x >> 2;   // image
    const int strip = (blockIdx.x & 3) * 8 + wv;   // 32 strips of 8 rows
    const int o0 = strip * SR;
    const int o1 = (o0 + SR < OH) ? (o0 + SR) : OH;   // last strip: 6 rows

    const size_t ib = (size_t)b * H * W;
    const float* predb = pred + ib;
    const float* rhsb  = rhs + (size_t)b * OH * OW;

    const float hr  = RR[ib + W + 2] - RR[ib + W + 1];
    const float hz  = ZZ[ib + 2 * W + 1] - ZZ[ib + W + 1];
    const float hr2 = hr * hr, hz2 = hz * hz;
    const float s   = -2.0f * (hr2 + hz2) / (hr2 * hz2);

    // Per-column folded coefficients over owned cols c0..c0+3.
    // Lane 63's .z/.w zeroed here: kills gs.z/gs.w for cols 254/255 forever
    // (also makes lane0's left-halo-from-lane63 read a guaranteed 0).
    const int c0 = 4 * l;
    float4 c4[9];
    {
        float4 invr;
        invr.x = 1.0f / RR[ib + W + (c0 + 1)];
        invr.y = 1.0f / RR[ib + W + (c0 + 2)];
        invr.z = 1.0f / RR[ib + W + (c0 + 3)];
        invr.w = 1.0f / RR[ib + W + ((c0 + 4 < W) ? (c0 + 4) : (W - 1))];
        const float* kl = KL + b * 9;
        const float* kd = KD + b * 9;
        const bool last = (l == 63);
#pragma unroll
        for (int t = 0; t < 9; ++t) {
            const float a = kl[t] * s, d = kd[t] * s;
            c4[t].x = fmaf(d, invr.x, a);
            c4[t].y = fmaf(d, invr.y, a);
            c4[t].z = last ? 0.f : fmaf(d, invr.z, a);
            c4[t].w = last ? 0.f : fmaf(d, invr.w, a);
        }
    }
    const float m23 = (c0 + 2 < OW) ? 1.f : 0.f;  // cols c0+2,c0+3 in range
    const float m0  = (l > 0) ? 1.f : 0.f;        // left-halo validity

    const int g0 = o0 - 1;
    const int rowlim = (o1 + 2 <= H - 1) ? (o1 + 2) : (H - 1); // last pred row needed&valid

    // Prologue: window rows g0, g0+1, g0+2 and their right-halos
    float4 p0 = make_float4(0.f, 0.f, 0.f, 0.f), p1, p2;
    if (g0 >= 0) p0 = *(const float4*)(predb + (size_t)g0 * W + c0);
    p1 = *(const float4*)(predb + (size_t)(g0 + 1) * W + c0);
    p2 = *(const float4*)(predb + (size_t)(g0 + 2) * W + c0);
    float h0x = __shfl(p0.x, l + 1, 64), h0y = __shfl(p0.y, l + 1, 64);
    float h1x = __shfl(p1.x, l + 1, 64), h1y = __shfl(p1.y, l + 1, 64);

    float4 ghA = make_float4(0.f, 0.f, 0.f, 0.f);   // gh row g-2
    float4 ghB = make_float4(0.f, 0.f, 0.f, 0.f);   // gh row g-1
    float2 rc0 = make_float2(0.f, 0.f), rc1 = make_float2(0.f, 0.f); // rhs row g-1
    float acc = 0.0f;

#define ROWC(gsv, p, nx, ny, t0)                                                  \
    gsv.x = fmaf(p.x, c4[t0].x, fmaf(p.y, c4[t0+1].x, fmaf(p.z, c4[t0+2].x, gsv.x))); \
    gsv.y = fmaf(p.y, c4[t0].y, fmaf(p.z, c4[t0+1].y, fmaf(p.w, c4[t0+2].y, gsv.y))); \
    gsv.z = fmaf(p.z, c4[t0].z, fmaf(p.w, c4[t0+1].z, fmaf(nx,  c4[t0+2].z, gsv.z))); \
    gsv.w = fmaf(p.w, c4[t0].w, fmaf(nx,  c4[t0+1].w, fmaf(ny,  c4[t0+2].w, gsv.w)));

    // Body covers output rows (g, g+1). Iteration count o1-g0+1 is 10 or 8:
    // always even, no tail.
    for (int g = g0; g < o1; g += 2) {
        // ---- body-top loads: pred rows g+3,g+4 ; rhs rows g,g+1 ----
        float4 pr3 = make_float4(0.f, 0.f, 0.f, 0.f);
        float4 pr4 = make_float4(0.f, 0.f, 0.f, 0.f);
        if (g + 3 <= rowlim) pr3 = *(const float4*)(predb + (size_t)(g + 3) * W + c0);
        if (g + 4 <= rowlim) pr4 = *(const float4*)(predb + (size_t)(g + 4) * W + c0);
        float2 rA0 = make_float2(0.f, 0.f), rA1 = make_float2(0.f, 0.f);
        float2 rB0 = make_float2(0.f, 0.f), rB1 = make_float2(0.f, 0.f);
        if (g >= o0 && g < o1) {
            const float* rr = rhsb + (size_t)g * OW + c0;
            rA0 = *(const float2*)rr;
            if (c0 + 2 < OW) rA1 = *(const float2*)(rr + 2);
        }
        if (g + 1 >= o0 && g + 1 < o1) {
            const float* rr = rhsb + (size_t)(g + 1) * OW + c0;
            rB0 = *(const float2*)rr;
            if (c0 + 2 < OW) rB1 = *(const float2*)(rr + 2);
        }

        // ---- phase A: GS_ope row g (rows g..g+2 = p0,p1,p2) ----
        const float h2x = __shfl(p2.x, l + 1, 64);
        const float h2y = __shfl(p2.y, l + 1, 64);
        float4 gs = make_float4(0.f, 0.f, 0.f, 0.f);
        if ((unsigned)g < (unsigned)OH) {
            ROWC(gs, p0, h0x, h0y, 0)
            ROWC(gs, p1, h1x, h1y, 3)
            ROWC(gs, p2, h2x, h2y, 6)
        }
        const float upA = __shfl(gs.w, l - 1, 64) * m0;
        const float dnA = __shfl(gs.x, l + 1, 64);   // lane63: dead via m23
        float4 ghC;
        ghC.x = fmaf(2.f, gs.x, upA  + gs.y);
        ghC.y = fmaf(2.f, gs.y, gs.x + gs.z);
        ghC.z = fmaf(2.f, gs.z, gs.y + gs.w);
        ghC.w = fmaf(2.f, gs.w, gs.z + dnA);
        if (g - 1 >= o0) {      // emit row g-1 (g-1 < o1 structurally)
            const float smx = (ghA.x + 2.f * ghB.x + ghC.x) * 0.0625f;
            const float smy = (ghA.y + 2.f * ghB.y + ghC.y) * 0.0625f;
            const float smz = (ghA.z + 2.f * ghB.z + ghC.z) * 0.0625f;
            const float smw = (ghA.w + 2.f * ghB.w + ghC.w) * 0.0625f;
            const float dx = smx - rc0.x;
            const float dy = smy - rc0.y;
            const float dz = (smz - rc1.x) * m23;
            const float dw = (smw - rc1.y) * m23;
            acc = fmaf(dx, dx, acc);
            acc = fmaf(dy, dy, acc);
            acc = fmaf(dz, dz, acc);
            acc = fmaf(dw, dw, acc);
        }

        // ---- phase B: GS_ope row g+1 (rows g+1..g+3 = p1,p2,pr3) ----
        const float h3x = __shfl(pr3.x, l + 1, 64);
        const float h3y = __shfl(pr3.y, l + 1, 64);
        float4 gt = make_float4(0.f, 0.f, 0.f, 0.f);
        if ((unsigned)(g + 1) < (unsigned)OH) {
            ROWC(gt, p1, h1x, h1y, 0)
            ROWC(gt, p2, h2x, h2y, 3)
            ROWC(gt, pr3, h3x, h3y, 6)
        }
        const float upB = __shfl(gt.w, l - 1, 64) * m0;
        const float dnB = __shfl(gt.x, l + 1, 64);
        float4 ghD;
        ghD.x = fmaf(2.f, gt.x, upB  + gt.y);
        ghD.y = fmaf(2.f, gt.y, gt.x + gt.z);
        ghD.z = fmaf(2.f, gt.z, gt.y + gt.w);
        ghD.w = fmaf(2.f, gt.w, gt.z + dnB);
        if (g >= o0) {          // emit row g (g < o1 from loop bound)
            const float smx = (ghB.x + 2.f * ghC.x + ghD.x) * 0.0625f;
            const float smy = (ghB.y + 2.f * ghC.y + ghD.y) * 0.0625f;
            const float smz = (ghB.z + 2.f * ghC.z + ghD.z) * 0.0625f;
            const float smw = (ghB.w + 2.f * ghC.w + ghD.w) * 0.0625f;
            const float dx = smx - rA0.x;
            const float dy = smy - rA0.y;
            const float dz = (smz - rA1.x) * m23;
            const float dw = (smw - rA1.y) * m23;
            acc = fmaf(dx, dx, acc);
            acc = fmaf(dy, dy, acc);
            acc = fmaf(dz, dz, acc);
            acc = fmaf(dw, dw, acc);
        }

        // ---- rotate (renaming, not data movement after unroll) ----
        p0 = p2; p1 = pr3; p2 = pr4;
        h0x = h2x; h0y = h2y; h1x = h3x; h1y = h3y;
        ghA = ghC; ghB = ghD;
        rc0 = rB0; rc1 = rB1;
    }
#undef ROWC

    // wave reduce -> block partial -> ONE contention-free store per block
#pragma unroll
    for (int off = 32; off > 0; off >>= 1)
        acc += __shfl_down(acc, off, 64);
    __shared__ float wsum[8];
    if (l == 0) wsum[wv] = acc;
    __syncthreads();
    if (tid == 0) {
        float t = 0.f;
#pragma unroll
        for (int k = 0; k < 8; ++k) t += wsum[k];
        partials[blockIdx.x] = t;
    }
}

// Second stage: reduce N partials -> out (single block). Applies inv_n, so no
// memset dispatch is needed anywhere.
__global__ __launch_bounds__(256)
void reduce_kernel(const float* __restrict__ partials, float* __restrict__ out,
                   int n, float inv_n)
{
    const int tid = threadIdx.x;
    float a = 0.0f;
    for (int i = tid; i < n; i += 256) a += partials[i];
#pragma unroll
    for (int off = 32; off > 0; off >>= 1)
        a += __shfl_down(a, off, 64);
    __shared__ float w[4];
    if ((tid & 63) == 0) w[tid >> 6] = a;
    __syncthreads();
    if (tid == 0) out[0] = ((w[0] + w[1]) + (w[2] + w[3])) * inv_n;
}

extern "C" void kernel_launch(void* const* d_in, const int* in_sizes, int n_in,
                              void* d_out, int out_size, void* d_ws, size_t ws_size,
                              hipStream_t stream) {
    const float* pred = (const float*)d_in[0];
    const float* rhs  = (const float*)d_in[1];
    const float* KL   = (const float*)d_in[2];
    const float* KD   = (const float*)d_in[3];
    const float* RR   = (const float*)d_in[4];
    const float* ZZ   = (const float*)d_in[5];
    // d_in[6] = Gauss kernel [[1,2,1],[2,4,2],[1,2,1]]/16 — hardcoded, separable
    float* out = (float*)d_out;

    const int B = in_sizes[2] / 9;   // 256
    const int nblocks = B * 4;       // 512-thread blocks, 8 strips each
    const float inv_n = 1.0f / ((float)B * 254.0f * 254.0f);

    float* partials = (float*)d_ws;  // nblocks floats
    pde_loss_kernel<<<dim3(nblocks), dim3(512), 0, stream>>>(
        pred, rhs, KL, KD, RR, ZZ, partials);
    reduce_kernel<<<dim3(1), dim3(256), 0, stream>>>(partials, out, nblocks, inv_n);
}